// Round 3
// baseline (23969.336 us; speedup 1.0000x reference)
//
#include <hip/hip_runtime.h>
#include <hip/hip_bf16.h>

#define NF 128
#define RBF 20
#define EPB 4   // edges per block-iteration
#define RPB 4   // rows per block-iteration (rowmlp)

__device__ __forceinline__ float sspf(float v) {
    return fmaxf(v, 0.f) + log1pf(__expf(-fabsf(v))) - 0.69314718055994531f;
}

// ---- per-row GEMV, 4 rows/iter: out = [ssp](in @ W [+ b]); dual branch via blockIdx.y
template<bool BIAS, bool ACT, typename OutT>
__global__ __launch_bounds__(128, 2)
void rowmlp_kernel(const float* __restrict__ in0, const float* __restrict__ in1,
                   const float* __restrict__ W0, const float* __restrict__ W1p,
                   const float* __restrict__ b0, const float* __restrict__ b1,
                   OutT* __restrict__ o0, OutT* __restrict__ o1, int N)
{
    const int c = threadIdx.x;                    // output column 0..127
    const float* in = blockIdx.y ? in1 : in0;
    const float* W  = blockIdx.y ? W1p : W0;
    OutT* out       = blockIdx.y ? o1  : o0;
    float bc = 0.f;
    if (BIAS) bc = (blockIdx.y ? b1 : b0)[c];

    float wreg[NF];
    #pragma unroll
    for (int k = 0; k < NF; ++k) wreg[k] = W[k * NF + c];

    __shared__ float rows[RPB * NF];

    const int nIter = (N + RPB - 1) / RPB;
    for (int it = blockIdx.x; it < nIter; it += gridDim.x) {
        const int n0 = it * RPB;
        __syncthreads();                           // prev-iter readers done
        // stage 4 rows (512 contiguous floats) coalesced
        #pragma unroll
        for (int k = 0; k < RPB; ++k) {
            int t = k * NF + c;
            int n = n0 + t / NF;
            rows[t] = (n < N) ? in[(size_t)n0 * NF + t] : 0.f;
        }
        __syncthreads();

        float acc[RPB];
        #pragma unroll
        for (int k = 0; k < RPB; ++k) acc[k] = bc;

        #pragma unroll
        for (int r = 0; r < NF; r += 4) {
            #pragma unroll
            for (int k = 0; k < RPB; ++k) {
                float4 r4 = *reinterpret_cast<const float4*>(&rows[k * NF + r]);
                float p0 = fmaf(r4.x, wreg[r],     r4.y * wreg[r + 1]);
                float p1 = fmaf(r4.z, wreg[r + 2], r4.w * wreg[r + 3]);
                acc[k] += p0 + p1;
            }
        }

        #pragma unroll
        for (int k = 0; k < RPB; ++k) {
            int n = n0 + k;
            if (n < N) {
                float v = ACT ? sspf(acc[k]) : acc[k];
                if constexpr (sizeof(OutT) == 2)
                    out[(size_t)n * NF + c] = __float2bfloat16(v);
                else
                    out[(size_t)n * NF + c] = v;
            }
        }
    }
}

// ---- fused edge kernel v2: 4 edges/iter, gather prefetch, 4 indep chains ----
__global__ __launch_bounds__(128, 2)
void edge_kernel(const float* __restrict__ f_ij,
                 const float* __restrict__ rcut,
                 const int* __restrict__ idx_i,
                 const int* __restrict__ idx_j,
                 const float* __restrict__ Wf1,
                 const float* __restrict__ bf1,
                 const float* __restrict__ Wf2,
                 const float* __restrict__ bf2,
                 const __hip_bfloat16* __restrict__ xf,
                 const __hip_bfloat16* __restrict__ yf,
                 float* __restrict__ conv_x,
                 float* __restrict__ conv_y,
                 int E)
{
    const int c = threadIdx.x;

    float w2reg[NF];
    #pragma unroll
    for (int k = 0; k < NF; ++k) w2reg[k] = Wf2[k * NF + c];
    float w1reg[RBF];
    #pragma unroll
    for (int r = 0; r < RBF; ++r) w1reg[r] = Wf1[r * NF + c];
    const float b1c = bf1[c];
    const float b2c = bf2[c];

    __shared__ float f_lds[EPB * RBF];
    __shared__ float h_lds[EPB * NF];

    const int nIter = (E + EPB - 1) / EPB;
    for (int it = blockIdx.x; it < nIter; it += gridDim.x) {
        const int e0 = it * EPB;

        // edge indices (broadcast loads) + gather prefetch BEFORE compute
        int   ii[EPB], jj[EPB];
        float ga[EPB], gb[EPB];   // ga: yf[j] (msg->x), gb: xf[i] (msg->y)
        float rc[EPB];
        #pragma unroll
        for (int k = 0; k < EPB; ++k) {
            int e = min(e0 + k, E - 1);
            ii[k] = idx_i[e];
            jj[k] = idx_j[e];
            rc[k] = rcut[e];
        }
        #pragma unroll
        for (int k = 0; k < EPB; ++k) {
            ga[k] = __bfloat162float(yf[(size_t)jj[k] * NF + c]);
            gb[k] = __bfloat162float(xf[(size_t)ii[k] * NF + c]);
        }

        __syncthreads();                    // prev-iter h/f readers done
        if (c < EPB * RBF) f_lds[c] = f_ij[(size_t)e0 * RBF + c];
        __syncthreads();

        // hidden layer: 4 independent 20-FMA chains
        #pragma unroll
        for (int k = 0; k < EPB; ++k) {
            float h = b1c;
            #pragma unroll
            for (int r = 0; r < RBF; ++r)
                h = fmaf(f_lds[k * RBF + r], w1reg[r], h);
            h_lds[k * NF + c] = sspf(h);
        }
        __syncthreads();

        // second layer: 4 edges x (2 partial chains)
        float accA[EPB], accB[EPB];
        #pragma unroll
        for (int k = 0; k < EPB; ++k) { accA[k] = b2c; accB[k] = 0.f; }
        #pragma unroll
        for (int r = 0; r < NF; r += 4) {
            #pragma unroll
            for (int k = 0; k < EPB; ++k) {
                float4 h4 = *reinterpret_cast<const float4*>(&h_lds[k * NF + r]);
                accA[k] = fmaf(h4.x, w2reg[r],     accA[k]);
                accA[k] = fmaf(h4.y, w2reg[r + 1], accA[k]);
                accB[k] = fmaf(h4.z, w2reg[r + 2], accB[k]);
                accB[k] = fmaf(h4.w, w2reg[r + 3], accB[k]);
            }
        }

        #pragma unroll
        for (int k = 0; k < EPB; ++k) {
            int e = e0 + k;
            if (e < E) {
                float w = (accA[k] + accB[k]) * rc[k];
                unsafeAtomicAdd(&conv_x[(size_t)ii[k] * NF + c], ga[k] * w);
                unsafeAtomicAdd(&conv_y[(size_t)jj[k] * NF + c], gb[k] * w);
            }
        }
    }
}

extern "C" void kernel_launch(void* const* d_in, const int* in_sizes, int n_in,
                              void* d_out, int out_size, void* d_ws, size_t ws_size,
                              hipStream_t stream)
{
    const float* x    = (const float*)d_in[0];
    const float* y    = (const float*)d_in[1];
    const float* f_ij = (const float*)d_in[2];
    const float* rcut = (const float*)d_in[3];
    const int* idx_i  = (const int*)d_in[4];
    const int* idx_j  = (const int*)d_in[5];
    const float* W_in2f   = (const float*)d_in[6];
    const float* W_in2f_y = (const float*)d_in[7];
    const float* Wf1 = (const float*)d_in[8];
    const float* bf1 = (const float*)d_in[9];
    const float* Wf2 = (const float*)d_in[10];
    const float* bf2 = (const float*)d_in[11];
    const float* Wx1 = (const float*)d_in[12];
    const float* bx1 = (const float*)d_in[13];
    const float* Wx2 = (const float*)d_in[14];
    const float* bx2 = (const float*)d_in[15];
    const float* Wy1 = (const float*)d_in[16];
    const float* by1 = (const float*)d_in[17];
    const float* Wy2 = (const float*)d_in[18];
    const float* by2 = (const float*)d_in[19];

    const int N = in_sizes[0] / NF;
    const int E = in_sizes[4];

    float* out = (float*)d_out;
    // d_out staging: xf/yf (bf16) live in the first half until edge_kernel
    // completes; then h (fp32, full d_out) overwrites them; layer2 in-place.
    __hip_bfloat16* xf = (__hip_bfloat16*)d_out;             // [N*NF] bf16
    __hip_bfloat16* yf = xf + (size_t)N * NF;                // [N*NF] bf16

    float* conv_x = (float*)d_ws;                            // [N*NF] fp32
    float* conv_y = conv_x + (size_t)N * NF;

    hipMemsetAsync(conv_x, 0, (size_t)2 * N * NF * sizeof(float), stream);

    // node projections (bias-free, no activation) -> bf16
    rowmlp_kernel<false, false, __hip_bfloat16><<<dim3(2048, 2), 128, 0, stream>>>(
        x, y, W_in2f, W_in2f_y, nullptr, nullptr, xf, yf, N);

    // fused edge filter + gather + scatter-add
    edge_kernel<<<dim3(4096), 128, 0, stream>>>(f_ij, rcut, idx_i, idx_j,
        Wf1, bf1, Wf2, bf2, xf, yf, conv_x, conv_y, E);

    // output MLP layer 1: h = ssp(conv @ W1 + b1) -> d_out (fp32)
    float* hx = out;                     // [N*NF]
    float* hy = out + (size_t)N * NF;    // [N*NF]
    rowmlp_kernel<true, true, float><<<dim3(2048, 2), 128, 0, stream>>>(
        conv_x, conv_y, Wx1, Wy1, bx1, by1, hx, hy, N);

    // output MLP layer 2: out = h @ W2 + b2  (in-place per-row, LDS-staged)
    rowmlp_kernel<true, false, float><<<dim3(2048, 2), 128, 0, stream>>>(
        hx, hy, Wx2, Wy2, bx2, by2, hx, hy, N);
}

// Round 4
// 1447.294 us; speedup vs baseline: 16.5615x; 16.5615x over previous
//
#include <hip/hip_runtime.h>
#include <hip/hip_bf16.h>

#define NF 128
#define RBF 20
#define TE 32            // edges per block (edge kernel)
#define TR 32            // rows per block (node kernel)

__device__ __forceinline__ float sspf(float v) {
    return fmaxf(v, 0.f) + log1pf(__expf(-fabsf(v))) - 0.69314718055994531f;
}

// ---------------- node-side tiled GEMM: out = [ssp](in @ W [+ b]) ----------
// 256 threads, 32-row tile, thread (c,g) computes 16 rows at column c.
template<bool BIAS, bool ACT, typename OutT>
__global__ __launch_bounds__(256, 4)
void node_tile_kernel(const float* in0, const float* in1,
                      const float* __restrict__ W0, const float* __restrict__ W1p,
                      const float* __restrict__ b0, const float* __restrict__ b1,
                      OutT* o0, OutT* o1, int N)
{
    const int tid = threadIdx.x;
    const int c = tid & (NF - 1);
    const int g = tid >> 7;              // 0 or 1
    const float* in = blockIdx.y ? in1 : in0;
    const float* W  = blockIdx.y ? W1p : W0;
    OutT* out       = blockIdx.y ? o1  : o0;
    float bc = 0.f;
    if (BIAS) bc = (blockIdx.y ? b1 : b0)[c];

    __shared__ float in_lds[TR][NF];     // [row][k], 16 KB

    const int n0 = blockIdx.x * TR;

    // stage 32 rows coalesced
    #pragma unroll
    for (int s = 0; s < TR * NF / 256; ++s) {
        int t = s * 256 + tid;
        int row = t >> 7, k = t & (NF - 1);
        int n = n0 + row;
        in_lds[row][k] = (n < N) ? in[(size_t)n * NF + k] : 0.f;
    }
    __syncthreads();

    float acc[16];
    #pragma unroll
    for (int e = 0; e < 16; ++e) acc[e] = bc;

    #pragma unroll 4
    for (int k = 0; k < NF; k += 4) {
        float4 w4;                        // W[k..k+3][c], L1/L2-resident
        w4.x = W[(size_t)(k    ) * NF + c];
        w4.y = W[(size_t)(k + 1) * NF + c];
        w4.z = W[(size_t)(k + 2) * NF + c];
        w4.w = W[(size_t)(k + 3) * NF + c];
        #pragma unroll
        for (int e = 0; e < 16; ++e) {
            float4 h4 = *reinterpret_cast<const float4*>(&in_lds[g * 16 + e][k]);
            acc[e] = fmaf(h4.x, w4.x, acc[e]);
            acc[e] = fmaf(h4.y, w4.y, acc[e]);
            acc[e] = fmaf(h4.z, w4.z, acc[e]);
            acc[e] = fmaf(h4.w, w4.w, acc[e]);
        }
    }
    __syncthreads();                      // allow in-place overwrite

    #pragma unroll
    for (int e = 0; e < 16; ++e) {
        int n = n0 + g * 16 + e;
        if (n < N) {
            float v = ACT ? sspf(acc[e]) : acc[e];
            if constexpr (sizeof(OutT) == 2)
                out[(size_t)n * NF + c] = __float2bfloat16(v);
            else
                out[(size_t)n * NF + c] = v;
        }
    }
}

// ---- fused edge kernel: filter MLP (tiled) + gather + scatter-add ----------
__global__ __launch_bounds__(256, 2)
void edge_tile_kernel(const float* __restrict__ f_ij,
                      const float* __restrict__ rcut,
                      const int* __restrict__ idx_i,
                      const int* __restrict__ idx_j,
                      const float* __restrict__ Wf1,
                      const float* __restrict__ bf1,
                      const float* __restrict__ Wf2,
                      const float* __restrict__ bf2,
                      const __hip_bfloat16* __restrict__ xf,
                      const __hip_bfloat16* __restrict__ yf,
                      float* __restrict__ conv_x,
                      float* __restrict__ conv_y,
                      int E)
{
    const int tid = threadIdx.x;
    const int c = tid & (NF - 1);
    const int g = tid >> 7;

    float w1reg[RBF];
    #pragma unroll
    for (int r = 0; r < RBF; ++r) w1reg[r] = Wf1[r * NF + c];
    const float b1c = bf1[c];
    const float b2c = bf2[c];

    __shared__ float f_lds[TE * RBF];    // 2.56 KB
    __shared__ float h_lds[TE][NF];      // 16 KB, [edge][hidden]

    const int e0 = blockIdx.x * TE;

    // prefetch indices + gathered messages for my 16 edges (hide under MLP)
    int ii[16], jj[16];
    float ga[16], gb[16], rc[16];
    #pragma unroll
    for (int e = 0; e < 16; ++e) {
        int eg = min(e0 + g * 16 + e, E - 1);
        ii[e] = idx_i[eg];
        jj[e] = idx_j[eg];
        rc[e] = rcut[eg];
    }
    #pragma unroll
    for (int e = 0; e < 16; ++e) {
        ga[e] = __bfloat162float(yf[(size_t)jj[e] * NF + c]);  // msg -> x-side
        gb[e] = __bfloat162float(xf[(size_t)ii[e] * NF + c]);  // msg -> y-side
    }

    // stage f tile (640 contiguous floats)
    for (int t = tid; t < TE * RBF; t += 256)
        f_lds[t] = f_ij[(size_t)e0 * RBF + t];
    __syncthreads();

    // phase 1: hidden-unit c for 16 edges
    #pragma unroll
    for (int e = 0; e < 16; ++e) {
        float hh = b1c;
        #pragma unroll
        for (int r = 0; r < RBF; ++r)
            hh = fmaf(f_lds[(g * 16 + e) * RBF + r], w1reg[r], hh);
        h_lds[g * 16 + e][c] = sspf(hh);
    }
    __syncthreads();

    // phase 2: out[e][c] = b2 + sum_k h[e][k] * W2[k][c]
    float acc[16];
    #pragma unroll
    for (int e = 0; e < 16; ++e) acc[e] = b2c;

    #pragma unroll 4
    for (int k = 0; k < NF; k += 4) {
        float4 w4;
        w4.x = Wf2[(size_t)(k    ) * NF + c];
        w4.y = Wf2[(size_t)(k + 1) * NF + c];
        w4.z = Wf2[(size_t)(k + 2) * NF + c];
        w4.w = Wf2[(size_t)(k + 3) * NF + c];
        #pragma unroll
        for (int e = 0; e < 16; ++e) {
            float4 h4 = *reinterpret_cast<const float4*>(&h_lds[g * 16 + e][k]);
            acc[e] = fmaf(h4.x, w4.x, acc[e]);
            acc[e] = fmaf(h4.y, w4.y, acc[e]);
            acc[e] = fmaf(h4.z, w4.z, acc[e]);
            acc[e] = fmaf(h4.w, w4.w, acc[e]);
        }
    }

    // phase 3: coalesced scatter (wave = 64 consecutive c)
    #pragma unroll
    for (int e = 0; e < 16; ++e) {
        int eg = e0 + g * 16 + e;
        if (eg < E) {
            float w = acc[e] * rc[e];
            unsafeAtomicAdd(&conv_x[(size_t)ii[e] * NF + c], ga[e] * w);
            unsafeAtomicAdd(&conv_y[(size_t)jj[e] * NF + c], gb[e] * w);
        }
    }
}

extern "C" void kernel_launch(void* const* d_in, const int* in_sizes, int n_in,
                              void* d_out, int out_size, void* d_ws, size_t ws_size,
                              hipStream_t stream)
{
    const float* x    = (const float*)d_in[0];
    const float* y    = (const float*)d_in[1];
    const float* f_ij = (const float*)d_in[2];
    const float* rcut = (const float*)d_in[3];
    const int* idx_i  = (const int*)d_in[4];
    const int* idx_j  = (const int*)d_in[5];
    const float* W_in2f   = (const float*)d_in[6];
    const float* W_in2f_y = (const float*)d_in[7];
    const float* Wf1 = (const float*)d_in[8];
    const float* bf1 = (const float*)d_in[9];
    const float* Wf2 = (const float*)d_in[10];
    const float* bf2 = (const float*)d_in[11];
    const float* Wx1 = (const float*)d_in[12];
    const float* bx1 = (const float*)d_in[13];
    const float* Wx2 = (const float*)d_in[14];
    const float* bx2 = (const float*)d_in[15];
    const float* Wy1 = (const float*)d_in[16];
    const float* by1 = (const float*)d_in[17];
    const float* Wy2 = (const float*)d_in[18];
    const float* by2 = (const float*)d_in[19];

    const int N = in_sizes[0] / NF;
    const int E = in_sizes[4];

    float* out = (float*)d_out;
    // d_out staging: xf/yf (bf16, 51.2 MB) until edge kernel done; then h
    // (fp32, full 102.4 MB) overwrites; final layer in-place.
    __hip_bfloat16* xf = (__hip_bfloat16*)d_out;
    __hip_bfloat16* yf = xf + (size_t)N * NF;

    float* conv_x = (float*)d_ws;
    float* conv_y = conv_x + (size_t)N * NF;

    hipMemsetAsync(conv_x, 0, (size_t)2 * N * NF * sizeof(float), stream);

    const int nodeTiles = (N + TR - 1) / TR;
    const int edgeTiles = (E + TE - 1) / TE;

    // projections (bias-free, no act) -> bf16
    node_tile_kernel<false, false, __hip_bfloat16>
        <<<dim3(nodeTiles, 2), 256, 0, stream>>>(
        x, y, W_in2f, W_in2f_y, nullptr, nullptr, xf, yf, N);

    // fused edge filter + gather + scatter
    edge_tile_kernel<<<dim3(edgeTiles), 256, 0, stream>>>(
        f_ij, rcut, idx_i, idx_j, Wf1, bf1, Wf2, bf2, xf, yf,
        conv_x, conv_y, E);

    // out MLP layer 1: h = ssp(conv @ W1 + b1) -> d_out fp32
    float* hx = out;
    float* hy = out + (size_t)N * NF;
    node_tile_kernel<true, true, float>
        <<<dim3(nodeTiles, 2), 256, 0, stream>>>(
        conv_x, conv_y, Wx1, Wy1, bx1, by1, hx, hy, N);

    // out MLP layer 2: out = h @ W2 + b2 (in-place, tile-staged)
    node_tile_kernel<true, false, float>
        <<<dim3(nodeTiles, 2), 256, 0, stream>>>(
        hx, hy, Wx2, Wy2, bx2, by2, hx, hy, N);
}

// Round 5
// 790.756 us; speedup vs baseline: 30.3119x; 1.8303x over previous
//
#include <hip/hip_runtime.h>
#include <hip/hip_bf16.h>

#define NF 128
#define RBF 20

using short8 = __attribute__((ext_vector_type(8))) short;
using f32x4  = __attribute__((ext_vector_type(4))) float;

__device__ __forceinline__ float sspf(float v) {
    return fmaxf(v, 0.f) + log1pf(__expf(-fabsf(v))) - 0.69314718055994531f;
}
__device__ __forceinline__ unsigned short f2bf(float f) {
    union { float f; unsigned u; } v; v.f = f;
    unsigned r = v.u + 0x7fffu + ((v.u >> 16) & 1u);
    return (unsigned short)(r >> 16);
}
__device__ __forceinline__ float bf2f(unsigned short s) {
    union { unsigned u; float f; } v; v.u = ((unsigned)s) << 16;
    return v.f;
}

// ---------------------------------------------------------------------------
// Edge kernel: 64 edges/block, 256 threads (4 waves).
// phase1 (VALU): h[64][128] = ssp(f@W1+b1) -> bf16 swizzled LDS
// phase2 (MFMA): out = h @ W2 (+b2), wave owns 32 cols, B-frags in VGPRs
// phase3: gather bf16 xf/yf + fp32 atomic scatter into conv_x/conv_y
// ---------------------------------------------------------------------------
__global__ __launch_bounds__(256, 2)
void edge_mfma_kernel(const float* __restrict__ f_ij,
                      const float* __restrict__ rcut,
                      const int* __restrict__ idx_i,
                      const int* __restrict__ idx_j,
                      const float* __restrict__ Wf1,
                      const float* __restrict__ bf1,
                      const float* __restrict__ Wf2,
                      const float* __restrict__ bf2v,
                      const unsigned short* __restrict__ xf,
                      const unsigned short* __restrict__ yf,
                      float* __restrict__ conv_x,
                      float* __restrict__ conv_y,
                      int E)
{
    const int tid = threadIdx.x;
    const int l = tid & 63, w = tid >> 6;
    const int lr = l & 15, lk = l >> 4;
    const int wcol0 = w * 32;

    __shared__ float f_lds[64 * RBF];
    __shared__ unsigned short Ash[64 * NF];
    __shared__ int ii_s[64], jj_s[64];
    __shared__ float rc_s[64];

    // B-frags: Wf2[k][col] -> bf16, kb<4, cb<2 (32 VGPRs)
    short8 bfr[4][2];
    #pragma unroll
    for (int kb = 0; kb < 4; ++kb)
        #pragma unroll
        for (int cb = 0; cb < 2; ++cb) {
            const int col = wcol0 + cb * 16 + lr;
            #pragma unroll
            for (int j = 0; j < 8; ++j)
                bfr[kb][cb][j] = (short)f2bf(Wf2[(size_t)(kb * 32 + lk * 8 + j) * NF + col]);
        }

    const int c = tid & (NF - 1);
    const int g = tid >> 7;
    float w1reg[RBF];
    #pragma unroll
    for (int r = 0; r < RBF; ++r) w1reg[r] = Wf1[r * NF + c];
    const float b1c  = bf1[c];
    const float b2c0 = bf2v[wcol0 + lr];
    const float b2c1 = bf2v[wcol0 + 16 + lr];

    const int e0 = blockIdx.x * 64;

    for (int t = tid; t < 64 * RBF; t += 256)
        f_lds[t] = f_ij[(size_t)e0 * RBF + t];
    if (tid < 64) {
        const int e = min(e0 + tid, E - 1);
        ii_s[tid] = idx_i[e];
        jj_s[tid] = idx_j[e];
        rc_s[tid] = rcut[e];
    }
    __syncthreads();

    // phase 1: hidden unit c for 32 edges (broadcast f reads)
    #pragma unroll 4
    for (int e8 = 0; e8 < 32; ++e8) {
        const int e = g * 32 + e8;
        float hv = b1c;
        #pragma unroll
        for (int r = 0; r < RBF; ++r)
            hv = fmaf(f_lds[e * RBF + r], w1reg[r], hv);
        Ash[e * NF + (c ^ ((e & 7) << 3))] = f2bf(sspf(hv));
    }
    __syncthreads();

    // phase 2: MFMA  D[64 edges][32 cols per wave]
    f32x4 acc[4][2] = {};
    #pragma unroll
    for (int rb = 0; rb < 4; ++rb) {
        short8 a[4];
        #pragma unroll
        for (int kb = 0; kb < 4; ++kb) {
            const int e  = rb * 16 + lr;
            const int k0 = kb * 32 + lk * 8;
            a[kb] = *reinterpret_cast<const short8*>(&Ash[e * NF + (k0 ^ ((e & 7) << 3))]);
        }
        #pragma unroll
        for (int cb = 0; cb < 2; ++cb)
            #pragma unroll
            for (int kb = 0; kb < 4; ++kb)
                acc[rb][cb] = __builtin_amdgcn_mfma_f32_16x16x32_bf16(
                    a[kb], bfr[kb][cb], acc[rb][cb], 0, 0, 0);
    }

    // phase 3: gather + scatter (16 consecutive cols per 16-lane group)
    #pragma unroll
    for (int rb = 0; rb < 4; ++rb) {
        #pragma unroll
        for (int cb = 0; cb < 2; ++cb) {
            const int col = wcol0 + cb * 16 + lr;
            const float bb = cb ? b2c1 : b2c0;
            #pragma unroll
            for (int q = 0; q < 4; ++q) {
                const int e = rb * 16 + lk * 4 + q;
                if (e0 + e < E) {
                    const int i = ii_s[e], j = jj_s[e];
                    const float wv = (acc[rb][cb][q] + bb) * rc_s[e];
                    const float ga = bf2f(yf[(size_t)j * NF + col]);
                    const float gb = bf2f(xf[(size_t)i * NF + col]);
                    unsafeAtomicAdd(&conv_x[(size_t)i * NF + col], ga * wv);
                    unsafeAtomicAdd(&conv_y[(size_t)j * NF + col], gb * wv);
                }
            }
        }
    }
}

// ---------------------------------------------------------------------------
// Node GEMM: out = [ssp](in @ W [+ b]), 64 rows/block, MFMA.
// SPLIT: hi/lo bf16 decomposition of A for near-fp32 input precision.
// ---------------------------------------------------------------------------
template<bool BIAS, bool ACT, bool SPLIT, typename OutT>
__global__ __launch_bounds__(256, 2)
void node_mfma_kernel(const float* in0, const float* in1,
                      const float* __restrict__ W0, const float* __restrict__ W1p,
                      const float* __restrict__ b0, const float* __restrict__ b1,
                      OutT* o0, OutT* o1, int N)
{
    const float* in = blockIdx.y ? in1 : in0;
    const float* W  = blockIdx.y ? W1p : W0;
    OutT* out       = blockIdx.y ? o1  : o0;

    const int tid = threadIdx.x;
    const int l = tid & 63, w = tid >> 6;
    const int lr = l & 15, lk = l >> 4;
    const int wcol0 = w * 32;

    __shared__ unsigned short Ahi[64 * NF];
    __shared__ unsigned short Alo[SPLIT ? 64 * NF : 64];

    short8 bfr[4][2];
    #pragma unroll
    for (int kb = 0; kb < 4; ++kb)
        #pragma unroll
        for (int cb = 0; cb < 2; ++cb) {
            const int col = wcol0 + cb * 16 + lr;
            #pragma unroll
            for (int j = 0; j < 8; ++j)
                bfr[kb][cb][j] = (short)f2bf(W[(size_t)(kb * 32 + lk * 8 + j) * NF + col]);
        }

    float bias0 = 0.f, bias1 = 0.f;
    if (BIAS) {
        const float* b = blockIdx.y ? b1 : b0;
        bias0 = b[wcol0 + lr];
        bias1 = b[wcol0 + 16 + lr];
    }

    const int n0 = blockIdx.x * 64;

    // stage A tile: fp32 coalesced load -> bf16 (hi[/lo]) swizzled LDS
    #pragma unroll
    for (int s = 0; s < 32; ++s) {
        const int t = s * 256 + tid;
        const int row = t >> 7, cc = t & (NF - 1);
        const float v = (n0 + row < N) ? in[(size_t)(n0 + row) * NF + cc] : 0.f;
        const unsigned short hi = f2bf(v);
        const int idx = row * NF + (cc ^ ((row & 7) << 3));
        Ahi[idx] = hi;
        if (SPLIT) Alo[idx] = f2bf(v - bf2f(hi));
    }
    __syncthreads();

    f32x4 acc[4][2] = {};
    #pragma unroll
    for (int rb = 0; rb < 4; ++rb) {
        short8 a[4], al[4];
        #pragma unroll
        for (int kb = 0; kb < 4; ++kb) {
            const int e  = rb * 16 + lr;
            const int k0 = kb * 32 + lk * 8;
            const int idx = e * NF + (k0 ^ ((e & 7) << 3));
            a[kb] = *reinterpret_cast<const short8*>(&Ahi[idx]);
            if (SPLIT) al[kb] = *reinterpret_cast<const short8*>(&Alo[idx]);
        }
        #pragma unroll
        for (int cb = 0; cb < 2; ++cb)
            #pragma unroll
            for (int kb = 0; kb < 4; ++kb) {
                acc[rb][cb] = __builtin_amdgcn_mfma_f32_16x16x32_bf16(
                    a[kb], bfr[kb][cb], acc[rb][cb], 0, 0, 0);
                if (SPLIT)
                    acc[rb][cb] = __builtin_amdgcn_mfma_f32_16x16x32_bf16(
                        al[kb], bfr[kb][cb], acc[rb][cb], 0, 0, 0);
            }
    }

    #pragma unroll
    for (int rb = 0; rb < 4; ++rb)
        #pragma unroll
        for (int cb = 0; cb < 2; ++cb) {
            const int col = wcol0 + cb * 16 + lr;
            #pragma unroll
            for (int q = 0; q < 4; ++q) {
                const int n = n0 + rb * 16 + lk * 4 + q;
                if (n < N) {
                    float v = acc[rb][cb][q] + (cb ? bias1 : bias0);
                    if (ACT) v = sspf(v);
                    if constexpr (sizeof(OutT) == 2)
                        out[(size_t)n * NF + col] = f2bf(v);
                    else
                        out[(size_t)n * NF + col] = v;
                }
            }
        }
}

extern "C" void kernel_launch(void* const* d_in, const int* in_sizes, int n_in,
                              void* d_out, int out_size, void* d_ws, size_t ws_size,
                              hipStream_t stream)
{
    const float* x    = (const float*)d_in[0];
    const float* y    = (const float*)d_in[1];
    const float* f_ij = (const float*)d_in[2];
    const float* rcut = (const float*)d_in[3];
    const int* idx_i  = (const int*)d_in[4];
    const int* idx_j  = (const int*)d_in[5];
    const float* W_in2f   = (const float*)d_in[6];
    const float* W_in2f_y = (const float*)d_in[7];
    const float* Wf1 = (const float*)d_in[8];
    const float* bf1 = (const float*)d_in[9];
    const float* Wf2 = (const float*)d_in[10];
    const float* bf2 = (const float*)d_in[11];
    const float* Wx1 = (const float*)d_in[12];
    const float* bx1 = (const float*)d_in[13];
    const float* Wx2 = (const float*)d_in[14];
    const float* bx2 = (const float*)d_in[15];
    const float* Wy1 = (const float*)d_in[16];
    const float* by1 = (const float*)d_in[17];
    const float* Wy2 = (const float*)d_in[18];
    const float* by2 = (const float*)d_in[19];

    const int N = in_sizes[0] / NF;
    const int E = in_sizes[4];

    // d_out staging: xf/yf (bf16 ushort) until edge kernel done; then hx/hy
    // (fp32) overwrite; final layer in-place.
    unsigned short* xf = (unsigned short*)d_out;
    unsigned short* yf = xf + (size_t)N * NF;
    float* hx = (float*)d_out;
    float* hy = hx + (size_t)N * NF;

    float* conv_x = (float*)d_ws;
    float* conv_y = conv_x + (size_t)N * NF;

    hipMemsetAsync(conv_x, 0, (size_t)2 * N * NF * sizeof(float), stream);

    const int nodeBlocks = (N + 63) / 64;
    const int edgeBlocks = (E + 63) / 64;

    // projections (bias-free, no act) -> bf16
    node_mfma_kernel<false, false, false, unsigned short>
        <<<dim3(nodeBlocks, 2), 256, 0, stream>>>(
        x, y, W_in2f, W_in2f_y, nullptr, nullptr, xf, yf, N);

    // fused edge filter + gather + scatter
    edge_mfma_kernel<<<dim3(edgeBlocks), 256, 0, stream>>>(
        f_ij, rcut, idx_i, idx_j, Wf1, bf1, Wf2, bf2, xf, yf,
        conv_x, conv_y, E);

    // out MLP layer 1: h = ssp(conv @ W1 + b1) -> fp32 (split-A for accuracy)
    node_mfma_kernel<true, true, true, float>
        <<<dim3(nodeBlocks, 2), 256, 0, stream>>>(
        conv_x, conv_y, Wx1, Wy1, bx1, by1, hx, hy, N);

    // out MLP layer 2: out = h @ W2 + b2 (in-place, split-A)
    node_mfma_kernel<true, false, true, float>
        <<<dim3(nodeBlocks, 2), 256, 0, stream>>>(
        hx, hy, Wx2, Wy2, bx2, by2, hx, hy, N);
}